// Round 1
// baseline (225.592 us; speedup 1.0000x reference)
//
#include <hip/hip_runtime.h>

#define BATCH 262144

typedef __attribute__((ext_vector_type(8))) short short8;
typedef __attribute__((ext_vector_type(4))) float f32x4;

// float -> bf16 bits, round-to-nearest-even
static __device__ __forceinline__ short f2b(float f) {
    unsigned u = __float_as_uint(f);
    return (short)((u + 0x7fffu + ((u >> 16) & 1u)) >> 16);
}
static __device__ __forceinline__ float sigm(float x) { return 1.0f / (1.0f + __expf(-x)); }
static __device__ __forceinline__ float tanh_f(float x) { return 1.0f - 2.0f / (__expf(2.0f * x) + 1.0f); }

// Convert all weight matrices to bf16 in workspace.
// layout (bf16 elems): [0:8192) w1, [8192:12288) w2, [12288:24576) w_ih,
//                      [24576:36864) w_hh, [36864:45056) lp_w1
__global__ void prep_weights(const float* __restrict__ w1, const float* __restrict__ w2,
                             const float* __restrict__ wih, const float* __restrict__ whh,
                             const float* __restrict__ lw1, unsigned short* __restrict__ wsb) {
    int i = blockIdx.x * 256 + threadIdx.x;
    float v;
    if (i < 8192) v = w1[i];
    else if (i < 12288) v = w2[i - 8192];
    else if (i < 24576) v = wih[i - 12288];
    else if (i < 36864) v = whh[i - 24576];
    else if (i < 45056) v = lw1[i - 36864];
    else return;
    wsb[i] = (unsigned short)f2b(v);
}

#define LDF 68    // f32 LDS row stride (64 + 4 pad) -> bank-friendly (68 % 32 == 4)
#define LDB 72    // bf16 LDS row stride (64 + 8 pad), 144 B rows, 16B-aligned
#define LDC 136   // bf16 LDS row stride for comb (128 + 8 pad), 272 B rows

static __device__ __forceinline__ short8 afrag_from_f32(const float* p) {
    f32x4 x0 = *(const f32x4*)p;
    f32x4 x1 = *(const f32x4*)(p + 4);
    short8 a;
#pragma unroll
    for (int j = 0; j < 4; ++j) { a[j] = f2b(x0[j]); a[j + 4] = f2b(x1[j]); }
    return a;
}

__global__ __launch_bounds__(256) void tgn_kernel(
    const int* __restrict__ pairs, const float* __restrict__ memory,
    const unsigned short* __restrict__ wsb,
    const float* __restrict__ b1, const float* __restrict__ b2,
    const float* __restrict__ bih, const float* __restrict__ bhh,
    const float* __restrict__ lb1, const float* __restrict__ lw2,
    const float* __restrict__ lb2, float* __restrict__ out)
{
    __shared__ __align__(16) float nmem[4][2][16][LDF];  // 34816 B: n1/n2 tiles, f32 master copies
    __shared__ __align__(16) short scr[4][2304];         // 18432 B: h1b[16][LDB] @0, msgb @1152; comb[16][LDC] reuses both

    const int tid = threadIdx.x;
    const int w  = tid >> 6;
    const int l  = tid & 63;
    const int lr = l & 15;       // M/N index within fragment
    const int lg = l >> 4;       // k-group / row-group

    const int tile = blockIdx.x * 4 + w;
    const int r0 = tile * 16;

    float* n1p = &nmem[w][0][0][0];
    float* n2p = &nmem[w][1][0][0];
    short* h1b  = &scr[w][0];
    short* msgb = &scr[w][1152];
    short* comb = &scr[w][0];

    const unsigned short* w1b  = wsb;          // [64][128]
    const unsigned short* w2b  = wsb + 8192;   // [64][64]
    const unsigned short* wihb = wsb + 12288;  // [192][64]
    const unsigned short* whhb = wsb + 24576;  // [192][64]
    const unsigned short* lw1b = wsb + 36864;  // [64][128]

    const f32x4 z4 = {0.0f, 0.0f, 0.0f, 0.0f};

    // ---- stage 0: gather. 16 lanes fetch one memory row (256 B) as float4 each ----
#pragma unroll
    for (int rr = 0; rr < 4; ++rr) {
        int row = rr * 4 + lg;
        long i1 = pairs[(r0 + row) * 2 + 0];
        long i2 = pairs[(r0 + row) * 2 + 1];
        f32x4 v1 = *(const f32x4*)(memory + i1 * 64 + lr * 4);
        f32x4 v2 = *(const f32x4*)(memory + i2 * 64 + lr * 4);
        *(f32x4*)(n1p + row * LDF + lr * 4) = v1;
        *(f32x4*)(n2p + row * LDF + lr * 4) = v2;
    }
    __syncthreads();

    // ---- stage 1: H1 = relu(X @ w1^T + b1), X = [n1|n2] (16x128) ----
    f32x4 acc[4];
#pragma unroll
    for (int nt = 0; nt < 4; ++nt) acc[nt] = z4;
#pragma unroll
    for (int kt = 0; kt < 4; ++kt) {
        int k = kt * 32 + lg * 8;  // 0..127
        const float* src = (k < 64) ? (n1p + lr * LDF + k) : (n2p + lr * LDF + (k - 64));
        short8 a = afrag_from_f32(src);
#pragma unroll
        for (int nt = 0; nt < 4; ++nt) {
            short8 b = *(const short8*)(w1b + (nt * 16 + lr) * 128 + kt * 32 + lg * 8);
            acc[nt] = __builtin_amdgcn_mfma_f32_16x16x32_bf16(a, b, acc[nt], 0, 0, 0);
        }
    }
#pragma unroll
    for (int nt = 0; nt < 4; ++nt) {
        float bv = b1[nt * 16 + lr];
#pragma unroll
        for (int r = 0; r < 4; ++r) {
            float v = fmaxf(acc[nt][r] + bv, 0.0f);
            h1b[(lg * 4 + r) * LDB + nt * 16 + lr] = f2b(v);
        }
    }
    __syncthreads();

    // ---- stage 2: MSG = H1 @ w2^T + b2 (16x64) ----
#pragma unroll
    for (int nt = 0; nt < 4; ++nt) acc[nt] = z4;
#pragma unroll
    for (int kt = 0; kt < 2; ++kt) {
        short8 a = *(const short8*)(h1b + lr * LDB + kt * 32 + lg * 8);
#pragma unroll
        for (int nt = 0; nt < 4; ++nt) {
            short8 b = *(const short8*)(w2b + (nt * 16 + lr) * 64 + kt * 32 + lg * 8);
            acc[nt] = __builtin_amdgcn_mfma_f32_16x16x32_bf16(a, b, acc[nt], 0, 0, 0);
        }
    }
#pragma unroll
    for (int nt = 0; nt < 4; ++nt) {
        float bv = b2[nt * 16 + lr];
#pragma unroll
        for (int r = 0; r < 4; ++r)
            msgb[(lg * 4 + r) * LDB + nt * 16 + lr] = f2b(acc[nt][r] + bv);
    }
    __syncthreads();

    // ---- stage 3: GI = MSG@w_ih^T, GH1 = n1@w_hh^T, GH2 = n2@w_hh^T (16x192 each) ----
    short8 am[2], a1[2], a2[2];
#pragma unroll
    for (int kt = 0; kt < 2; ++kt) {
        am[kt] = *(const short8*)(msgb + lr * LDB + kt * 32 + lg * 8);
        a1[kt] = afrag_from_f32(n1p + lr * LDF + kt * 32 + lg * 8);
        a2[kt] = afrag_from_f32(n2p + lr * LDF + kt * 32 + lg * 8);
    }
    f32x4 gi[12], gh1[12], gh2[12];
#pragma unroll
    for (int nt = 0; nt < 12; ++nt) { gi[nt] = z4; gh1[nt] = z4; gh2[nt] = z4; }
#pragma unroll
    for (int nt = 0; nt < 12; ++nt) {
#pragma unroll
        for (int kt = 0; kt < 2; ++kt) {
            short8 bi = *(const short8*)(wihb + (nt * 16 + lr) * 64 + kt * 32 + lg * 8);
            short8 bh = *(const short8*)(whhb + (nt * 16 + lr) * 64 + kt * 32 + lg * 8);
            gi[nt]  = __builtin_amdgcn_mfma_f32_16x16x32_bf16(am[kt], bi, gi[nt], 0, 0, 0);
            gh1[nt] = __builtin_amdgcn_mfma_f32_16x16x32_bf16(a1[kt], bh, gh1[nt], 0, 0, 0);
            gh2[nt] = __builtin_amdgcn_mfma_f32_16x16x32_bf16(a2[kt], bh, gh2[nt], 0, 0, 0);
        }
    }

    // ---- stage 4: GRU elementwise (C-layout: col j = nt*16+lr, row = lg*4+r) ----
#pragma unroll
    for (int nt = 0; nt < 4; ++nt) {
        int j = nt * 16 + lr;
        float bir = bih[j],       bhr = bhh[j];
        float biz = bih[64 + j],  bhz = bhh[64 + j];
        float bin = bih[128 + j], bhn = bhh[128 + j];
#pragma unroll
        for (int r = 0; r < 4; ++r) {
            int row = lg * 4 + r;
            float i_r = gi[nt][r] + bir;
            float i_z = gi[nt + 4][r] + biz;
            float i_n = gi[nt + 8][r] + bin;
            // node 1
            float h_r = gh1[nt][r] + bhr, h_z = gh1[nt + 4][r] + bhz, h_n = gh1[nt + 8][r] + bhn;
            float rg = sigm(i_r + h_r), zg = sigm(i_z + h_z);
            float ng = tanh_f(i_n + rg * h_n);
            float h  = n1p[row * LDF + j];
            comb[row * LDC + j] = f2b((1.0f - zg) * ng + zg * h);
            // node 2
            h_r = gh2[nt][r] + bhr; h_z = gh2[nt + 4][r] + bhz; h_n = gh2[nt + 8][r] + bhn;
            rg = sigm(i_r + h_r); zg = sigm(i_z + h_z);
            ng = tanh_f(i_n + rg * h_n);
            h  = n2p[row * LDF + j];
            comb[row * LDC + 64 + j] = f2b((1.0f - zg) * ng + zg * h);
        }
    }
    __syncthreads();

    // ---- stage 5: H = relu(COMB @ lp_w1^T + lb1) (16x64) ----
    f32x4 acc5[4];
#pragma unroll
    for (int nt = 0; nt < 4; ++nt) acc5[nt] = z4;
#pragma unroll
    for (int kt = 0; kt < 4; ++kt) {
        short8 a = *(const short8*)(comb + lr * LDC + kt * 32 + lg * 8);
#pragma unroll
        for (int nt = 0; nt < 4; ++nt) {
            short8 b = *(const short8*)(lw1b + (nt * 16 + lr) * 128 + kt * 32 + lg * 8);
            acc5[nt] = __builtin_amdgcn_mfma_f32_16x16x32_bf16(a, b, acc5[nt], 0, 0, 0);
        }
    }

    // ---- stage 6: out = sigmoid(H @ lp_w2^T + lb2), reduce over 64 cols ----
    float part[4] = {0.0f, 0.0f, 0.0f, 0.0f};
#pragma unroll
    for (int nt = 0; nt < 4; ++nt) {
        float w2v = lw2[nt * 16 + lr];
        float bv  = lb1[nt * 16 + lr];
#pragma unroll
        for (int r = 0; r < 4; ++r) {
            float hv = fmaxf(acc5[nt][r] + bv, 0.0f);
            part[r] += hv * w2v;
        }
    }
    float lb2v = lb2[0];
#pragma unroll
    for (int r = 0; r < 4; ++r) {
        float p = part[r];
        p += __shfl_xor(p, 1);
        p += __shfl_xor(p, 2);
        p += __shfl_xor(p, 4);
        p += __shfl_xor(p, 8);
        if (lr == 0) out[r0 + lg * 4 + r] = sigm(p + lb2v);
    }
}

extern "C" void kernel_launch(void* const* d_in, const int* in_sizes, int n_in,
                              void* d_out, int out_size, void* d_ws, size_t ws_size,
                              hipStream_t stream) {
    const int*   pairs  = (const int*)d_in[0];
    const float* memory = (const float*)d_in[1];
    const float* w1  = (const float*)d_in[2];
    const float* b1  = (const float*)d_in[3];
    const float* w2  = (const float*)d_in[4];
    const float* b2  = (const float*)d_in[5];
    const float* wih = (const float*)d_in[6];
    const float* whh = (const float*)d_in[7];
    const float* bih = (const float*)d_in[8];
    const float* bhh = (const float*)d_in[9];
    const float* lw1 = (const float*)d_in[10];
    const float* lb1 = (const float*)d_in[11];
    const float* lw2 = (const float*)d_in[12];
    const float* lb2 = (const float*)d_in[13];
    unsigned short* wsb = (unsigned short*)d_ws;

    prep_weights<<<176, 256, 0, stream>>>(w1, w2, wih, whh, lw1, wsb);
    tgn_kernel<<<BATCH / 64, 256, 0, stream>>>(pairs, memory, wsb, b1, b2, bih, bhh,
                                               lb1, lw2, lb2, (float*)d_out);
}

// Round 3
// 179.773 us; speedup vs baseline: 1.2549x; 1.2549x over previous
//
#include <hip/hip_runtime.h>

#define BATCH 262144

typedef __attribute__((ext_vector_type(8))) short short8;
typedef __attribute__((ext_vector_type(4))) short s16x4;
typedef __attribute__((ext_vector_type(4))) float f32x4;

// float -> bf16 bits, round-to-nearest-even
static __device__ __forceinline__ short f2b(float f) {
    unsigned u = __float_as_uint(f);
    return (short)((u + 0x7fffu + ((u >> 16) & 1u)) >> 16);
}
static __device__ __forceinline__ float b2f(short s) {
    return __uint_as_float(((unsigned)(unsigned short)s) << 16);
}
static __device__ __forceinline__ float sigm(float x) { return 1.0f / (1.0f + __expf(-x)); }
static __device__ __forceinline__ float tanh_f(float x) { return 1.0f - 2.0f / (__expf(2.0f * x) + 1.0f); }

// All LDS buffers are PER-WAVE: no cross-wave sharing -> no __syncthreads needed.
// DS ops complete in order within a wave; lgkmcnt(0) makes prior ds_writes visible.
#define WAVE_FENCE() asm volatile("s_waitcnt lgkmcnt(0)" ::: "memory")

// Convert all weight matrices to bf16 in workspace.
// layout (bf16 elems): [0:8192) w1, [8192:12288) w2, [12288:24576) w_ih,
//                      [24576:36864) w_hh, [36864:45056) lp_w1
__global__ void prep_weights(const float* __restrict__ w1, const float* __restrict__ w2,
                             const float* __restrict__ wih, const float* __restrict__ whh,
                             const float* __restrict__ lw1, unsigned short* __restrict__ wsb) {
    int i = blockIdx.x * 256 + threadIdx.x;
    float v;
    if (i < 8192) v = w1[i];
    else if (i < 12288) v = w2[i - 8192];
    else if (i < 24576) v = wih[i - 12288];
    else if (i < 36864) v = whh[i - 24576];
    else if (i < 45056) v = lw1[i - 36864];
    else return;
    wsb[i] = (unsigned short)f2b(v);
}

#define LDB 72    // bf16 LDS row stride (64 + 8 pad), rows 144 B, 16B-aligned
#define LDC 136   // bf16 LDS row stride for comb (128 + 8 pad)

__global__ __launch_bounds__(256, 4) void tgn_kernel(
    const int* __restrict__ pairs, const float* __restrict__ memory,
    const unsigned short* __restrict__ wsb,
    const float* __restrict__ b1, const float* __restrict__ b2,
    const float* __restrict__ bih, const float* __restrict__ bhh,
    const float* __restrict__ lb1, const float* __restrict__ lw2,
    const float* __restrict__ lb2, float* __restrict__ out)
{
    __shared__ __align__(16) short nmem[4][2][16][LDB];  // 18432 B: n1/n2 bf16
    __shared__ __align__(16) short scr[4][2304];         // 18432 B: h1b@0, msgb@1152; comb reuses

    const int tid = threadIdx.x;
    const int w  = tid >> 6;
    const int l  = tid & 63;
    const int lr = l & 15;       // M/N index within fragment
    const int lg = l >> 4;       // k-group / row-group

    const int r0 = (blockIdx.x * 4 + w) * 16;

    short* n1b  = &nmem[w][0][0][0];
    short* n2b  = &nmem[w][1][0][0];
    short* h1b  = &scr[w][0];
    short* msgb = &scr[w][1152];
    short* comb = &scr[w][0];

    const unsigned short* w1b  = wsb;          // [64][128]
    const unsigned short* w2b  = wsb + 8192;   // [64][64]
    const unsigned short* wihb = wsb + 12288;  // [192][64]
    const unsigned short* whhb = wsb + 24576;  // [192][64]
    const unsigned short* lw1b = wsb + 36864;  // [64][128]

    const f32x4 z4 = {0.0f, 0.0f, 0.0f, 0.0f};

    // ---- stage 0: gather -> bf16 LDS. 16 lanes fetch one 256B memory row each ----
#pragma unroll
    for (int rr = 0; rr < 4; ++rr) {
        int row = rr * 4 + lg;
        long i1 = pairs[(r0 + row) * 2 + 0];
        long i2 = pairs[(r0 + row) * 2 + 1];
        f32x4 v1 = *(const f32x4*)(memory + i1 * 64 + lr * 4);
        f32x4 v2 = *(const f32x4*)(memory + i2 * 64 + lr * 4);
        s16x4 c1, c2;
#pragma unroll
        for (int j = 0; j < 4; ++j) { c1[j] = f2b(v1[j]); c2[j] = f2b(v2[j]); }
        *(s16x4*)(n1b + row * LDB + lr * 4) = c1;
        *(s16x4*)(n2b + row * LDB + lr * 4) = c2;
    }
    WAVE_FENCE();

    // ---- stage 1: H1 = relu(X @ w1^T + b1), X = [n1|n2] (16x128) ----
    f32x4 acc[4];
#pragma unroll
    for (int nt = 0; nt < 4; ++nt) acc[nt] = z4;
#pragma unroll
    for (int kt = 0; kt < 4; ++kt) {
        const short* ap = (kt < 2 ? n1b : n2b) + lr * LDB + (kt & 1) * 32 + lg * 8;
        short8 a = *(const short8*)ap;
#pragma unroll
        for (int nt = 0; nt < 4; ++nt) {
            short8 b = *(const short8*)(w1b + (nt * 16 + lr) * 128 + kt * 32 + lg * 8);
            acc[nt] = __builtin_amdgcn_mfma_f32_16x16x32_bf16(a, b, acc[nt], 0, 0, 0);
        }
    }
#pragma unroll
    for (int nt = 0; nt < 4; ++nt) {
        float bv = b1[nt * 16 + lr];
#pragma unroll
        for (int r = 0; r < 4; ++r)
            h1b[(lg * 4 + r) * LDB + nt * 16 + lr] = f2b(fmaxf(acc[nt][r] + bv, 0.0f));
    }
    WAVE_FENCE();

    // ---- stage 2: MSG = H1 @ w2^T + b2 (16x64) ----
#pragma unroll
    for (int nt = 0; nt < 4; ++nt) acc[nt] = z4;
#pragma unroll
    for (int kt = 0; kt < 2; ++kt) {
        short8 a = *(const short8*)(h1b + lr * LDB + kt * 32 + lg * 8);
#pragma unroll
        for (int nt = 0; nt < 4; ++nt) {
            short8 b = *(const short8*)(w2b + (nt * 16 + lr) * 64 + kt * 32 + lg * 8);
            acc[nt] = __builtin_amdgcn_mfma_f32_16x16x32_bf16(a, b, acc[nt], 0, 0, 0);
        }
    }
#pragma unroll
    for (int nt = 0; nt < 4; ++nt) {
        float bv = b2[nt * 16 + lr];
#pragma unroll
        for (int r = 0; r < 4; ++r)
            msgb[(lg * 4 + r) * LDB + nt * 16 + lr] = f2b(acc[nt][r] + bv);
    }
    WAVE_FENCE();

    // ---- stage 3+4 fused: per column-block nt, compute 9 gate tiles then GRU ----
    short8 am[2], a1[2], a2[2];
#pragma unroll
    for (int kt = 0; kt < 2; ++kt) {
        am[kt] = *(const short8*)(msgb + lr * LDB + kt * 32 + lg * 8);
        a1[kt] = *(const short8*)(n1b + lr * LDB + kt * 32 + lg * 8);
        a2[kt] = *(const short8*)(n2b + lr * LDB + kt * 32 + lg * 8);
    }
#pragma unroll
    for (int nt = 0; nt < 4; ++nt) {
        f32x4 gir = z4, giz = z4, gin = z4;
        f32x4 g1r = z4, g1z = z4, g1n = z4;
        f32x4 g2r = z4, g2z = z4, g2n = z4;
#pragma unroll
        for (int kt = 0; kt < 2; ++kt) {
            int ko = kt * 32 + lg * 8;
            short8 bir = *(const short8*)(wihb + ((0 + nt) * 16 + lr) * 64 + ko);
            short8 biz = *(const short8*)(wihb + ((4 + nt) * 16 + lr) * 64 + ko);
            short8 bin = *(const short8*)(wihb + ((8 + nt) * 16 + lr) * 64 + ko);
            short8 bhr = *(const short8*)(whhb + ((0 + nt) * 16 + lr) * 64 + ko);
            short8 bhz = *(const short8*)(whhb + ((4 + nt) * 16 + lr) * 64 + ko);
            short8 bhn = *(const short8*)(whhb + ((8 + nt) * 16 + lr) * 64 + ko);
            gir = __builtin_amdgcn_mfma_f32_16x16x32_bf16(am[kt], bir, gir, 0, 0, 0);
            giz = __builtin_amdgcn_mfma_f32_16x16x32_bf16(am[kt], biz, giz, 0, 0, 0);
            gin = __builtin_amdgcn_mfma_f32_16x16x32_bf16(am[kt], bin, gin, 0, 0, 0);
            g1r = __builtin_amdgcn_mfma_f32_16x16x32_bf16(a1[kt], bhr, g1r, 0, 0, 0);
            g1z = __builtin_amdgcn_mfma_f32_16x16x32_bf16(a1[kt], bhz, g1z, 0, 0, 0);
            g1n = __builtin_amdgcn_mfma_f32_16x16x32_bf16(a1[kt], bhn, g1n, 0, 0, 0);
            g2r = __builtin_amdgcn_mfma_f32_16x16x32_bf16(a2[kt], bhr, g2r, 0, 0, 0);
            g2z = __builtin_amdgcn_mfma_f32_16x16x32_bf16(a2[kt], bhz, g2z, 0, 0, 0);
            g2n = __builtin_amdgcn_mfma_f32_16x16x32_bf16(a2[kt], bhn, g2n, 0, 0, 0);
        }
        int j = nt * 16 + lr;
        float bir_ = bih[j], biz_ = bih[64 + j], bin_ = bih[128 + j];
        float bhr_ = bhh[j], bhz_ = bhh[64 + j], bhn_ = bhh[128 + j];
#pragma unroll
        for (int r = 0; r < 4; ++r) {
            int row = lg * 4 + r;
            float i_r = gir[r] + bir_;
            float i_z = giz[r] + biz_;
            float i_n = gin[r] + bin_;
            // node 1
            float rg = sigm(i_r + g1r[r] + bhr_);
            float zg = sigm(i_z + g1z[r] + bhz_);
            float ng = tanh_f(i_n + rg * (g1n[r] + bhn_));
            float h  = b2f(n1b[row * LDB + j]);
            comb[row * LDC + j] = f2b((1.0f - zg) * ng + zg * h);
            // node 2
            rg = sigm(i_r + g2r[r] + bhr_);
            zg = sigm(i_z + g2z[r] + bhz_);
            ng = tanh_f(i_n + rg * (g2n[r] + bhn_));
            h  = b2f(n2b[row * LDB + j]);
            comb[row * LDC + 64 + j] = f2b((1.0f - zg) * ng + zg * h);
        }
    }
    WAVE_FENCE();

    // ---- stage 5: H = relu(COMB @ lp_w1^T + lb1) (16x64) ----
    f32x4 acc5[4];
#pragma unroll
    for (int nt = 0; nt < 4; ++nt) acc5[nt] = z4;
#pragma unroll
    for (int kt = 0; kt < 4; ++kt) {
        short8 a = *(const short8*)(comb + lr * LDC + kt * 32 + lg * 8);
#pragma unroll
        for (int nt = 0; nt < 4; ++nt) {
            short8 b = *(const short8*)(lw1b + (nt * 16 + lr) * 128 + kt * 32 + lg * 8);
            acc5[nt] = __builtin_amdgcn_mfma_f32_16x16x32_bf16(a, b, acc5[nt], 0, 0, 0);
        }
    }

    // ---- stage 6: out = sigmoid(H @ lp_w2^T + lb2), reduce over 64 cols ----
    float part[4] = {0.0f, 0.0f, 0.0f, 0.0f};
#pragma unroll
    for (int nt = 0; nt < 4; ++nt) {
        float w2v = lw2[nt * 16 + lr];
        float bv  = lb1[nt * 16 + lr];
#pragma unroll
        for (int r = 0; r < 4; ++r)
            part[r] += fmaxf(acc5[nt][r] + bv, 0.0f) * w2v;
    }
    float lb2v = lb2[0];
#pragma unroll
    for (int r = 0; r < 4; ++r) {
        float p = part[r];
        p += __shfl_xor(p, 1);
        p += __shfl_xor(p, 2);
        p += __shfl_xor(p, 4);
        p += __shfl_xor(p, 8);
        if (lr == 0) out[r0 + lg * 4 + r] = sigm(p + lb2v);
    }
}

extern "C" void kernel_launch(void* const* d_in, const int* in_sizes, int n_in,
                              void* d_out, int out_size, void* d_ws, size_t ws_size,
                              hipStream_t stream) {
    const int*   pairs  = (const int*)d_in[0];
    const float* memory = (const float*)d_in[1];
    const float* w1  = (const float*)d_in[2];
    const float* b1  = (const float*)d_in[3];
    const float* w2  = (const float*)d_in[4];
    const float* b2  = (const float*)d_in[5];
    const float* wih = (const float*)d_in[6];
    const float* whh = (const float*)d_in[7];
    const float* bih = (const float*)d_in[8];
    const float* bhh = (const float*)d_in[9];
    const float* lw1 = (const float*)d_in[10];
    const float* lb1 = (const float*)d_in[11];
    const float* lw2 = (const float*)d_in[12];
    const float* lb2 = (const float*)d_in[13];
    unsigned short* wsb = (unsigned short*)d_ws;

    prep_weights<<<176, 256, 0, stream>>>(w1, w2, wih, whh, lw1, wsb);
    tgn_kernel<<<BATCH / 64, 256, 0, stream>>>(pairs, memory, wsb, b1, b2, bih, bhh,
                                               lb1, lw2, lb2, (float*)d_out);
}